// Round 5
// baseline (75.849 us; speedup 1.0000x reference)
//
#include <hip/hip_runtime.h>

#define K_EPS2 1e-8f
#define K_TINY 1e-12f
#define KEY_EDGE_WEIGHT 0.1f

__device__ __forceinline__ float3 f3(float x, float y, float z) { return make_float3(x, y, z); }
__device__ __forceinline__ float3 add3(float3 a, float3 b) { return f3(a.x + b.x, a.y + b.y, a.z + b.z); }
__device__ __forceinline__ float3 sub3(float3 a, float3 b) { return f3(a.x - b.x, a.y - b.y, a.z - b.z); }
__device__ __forceinline__ float3 scl3(float s, float3 a) { return f3(s * a.x, s * a.y, s * a.z); }
__device__ __forceinline__ float dot3(float3 a, float3 b) { return a.x * b.x + a.y * b.y + a.z * b.z; }
__device__ __forceinline__ float3 cross3(float3 a, float3 b) {
    return f3(a.y * b.z - a.z * b.y,
              a.z * b.x - a.x * b.z,
              a.x * b.y - a.y * b.x);
}

__device__ __forceinline__ float3 qrot(float3 qv, float qw, float3 v) {
    float3 t = add3(cross3(qv, v), scl3(qw, v));
    return add3(v, scl3(2.0f, cross3(qv, t)));
}

__device__ __forceinline__ void qmul(float3 v1, float w1, float3 v2, float w2,
                                     float3* v, float* w) {
    *w = w1 * w2 - dot3(v1, v2);
    *v = add3(add3(scl3(w1, v2), scl3(w2, v1)), cross3(v1, v2));
}

// 2 edges per thread: all loads issued up-front (two independent latency
// chains + deep VMEM queue), then compute, then 3x float4 coalesced store.
__global__ __launch_bounds__(256) void PoseGraph_kernel(
    const float* __restrict__ nodes,   // [N,7]  t(3), q(4) xyzw
    const float* __restrict__ poses,   // [E,4,4] row-major
    const int*   __restrict__ edges,   // [E,2]  int32
    float*       __restrict__ out,     // [E,6]  tau(3), phi(3)
    int E) {
    int t = blockIdx.x * blockDim.x + threadIdx.x;
    int e0 = t * 2;
    if (e0 >= E) return;
    bool full = (e0 + 1 < E);

    int eidx[2];
    eidx[0] = e0;
    eidx[1] = full ? (e0 + 1) : e0;

    // ---- index loads (16B aligned int4 when both edges present) ----
    int idx1[2], idx2[2];
    if (full) {
        int4 ij4 = *(const int4*)(edges + (size_t)4 * t);
        idx1[0] = ij4.x; idx2[0] = ij4.y;
        idx1[1] = ij4.z; idx2[1] = ij4.w;
    } else {
        int2 a = *(const int2*)(edges + (size_t)2 * e0);
        idx1[0] = idx1[1] = a.x;
        idx2[0] = idx2[1] = a.y;
    }

    // ---- pose loads (independent of indices — issue early) ----
    float4 r0[2], r1[2], r2[2];
    #pragma unroll
    for (int k = 0; k < 2; ++k) {
        const float4* p4 = (const float4*)(poses + (size_t)eidx[k] * 16);
        r0[k] = p4[0];
        r1[k] = p4[1];
        r2[k] = p4[2];
    }

    // ---- node gathers, both edges (L2-resident table, 2.8 MB) ----
    float nA[2][7], nB[2][7];
    #pragma unroll
    for (int k = 0; k < 2; ++k) {
        const float* pa = nodes + (size_t)idx1[k] * 7;
        const float* pb = nodes + (size_t)idx2[k] * 7;
        #pragma unroll
        for (int j = 0; j < 7; ++j) {
            nA[k][j] = pa[j];
            nB[k][j] = pb[j];
        }
    }

    // ---- compute both edges ----
    float res[2][6];
    #pragma unroll
    for (int k = 0; k < 2; ++k) {
        float3 t1  = f3(nA[k][0], nA[k][1], nA[k][2]);
        float3 q1v = f3(nA[k][3], nA[k][4], nA[k][5]);
        float  q1w = nA[k][6];
        float3 t2  = f3(nB[k][0], nB[k][1], nB[k][2]);
        float3 q2v = f3(nB[k][3], nB[k][4], nB[k][5]);
        float  q2w = nB[k][6];

        // relative node transform, q1i = conj(q1)
        float3 q1iv = f3(-q1v.x, -q1v.y, -q1v.z);
        float3 t12 = qrot(q1iv, q1w, sub3(t2, t1));
        float3 q12v; float q12w;
        qmul(q1iv, q1w, q2v, q2w, &q12v, &q12w);

        // pose matrix -> (tp, qp), branchless copysign mat2SE3
        float m00 = r0[k].x, m01 = r0[k].y, m02 = r0[k].z;
        float m10 = r1[k].x, m11 = r1[k].y, m12 = r1[k].z;
        float m20 = r2[k].x, m21 = r2[k].y, m22 = r2[k].z;
        float3 tp = f3(r0[k].w, r1[k].w, r2[k].w);

        float qpw = 0.5f * sqrtf(fmaxf(1.0f + m00 + m11 + m22, K_TINY));
        float qpx = ((m21 - m12 >= 0.0f) ? 0.5f : -0.5f) * sqrtf(fmaxf(1.0f + m00 - m11 - m22, K_TINY));
        float qpy = ((m02 - m20 >= 0.0f) ? 0.5f : -0.5f) * sqrtf(fmaxf(1.0f - m00 + m11 - m22, K_TINY));
        float qpz = ((m10 - m01 >= 0.0f) ? 0.5f : -0.5f) * sqrtf(fmaxf(1.0f - m00 - m11 + m22, K_TINY));
        float3 qpv = f3(qpx, qpy, qpz);

        // compose error transform
        float3 te = add3(tp, qrot(qpv, qpw, t12));
        float3 qev; float qew;
        qmul(qpv, qpw, q12v, q12w, &qev, &qew);

        // SO3 log
        float s = (qew < 0.0f) ? -1.0f : 1.0f;
        float3 v = scl3(s, qev);
        float w = s * qew;
        float nn2 = dot3(v, v);
        float scale;
        if (nn2 > K_EPS2) {
            float n = sqrtf(nn2);
            scale = 2.0f * atan2f(n, w) / n;
        } else {
            scale = 2.0f / w - 2.0f * nn2 / (3.0f * w * w * w);
        }
        float3 phi = scl3(scale, v);

        // SE3 log tail: V^{-1} * t
        float th2 = dot3(phi, phi);
        float coef;
        if (th2 > K_EPS2) {
            float th = sqrtf(th2);
            float half = 0.5f * th;
            float sh = sinf(half);
            float ch = cosf(half);
            coef = (1.0f - half * ch / sh) / th2;
        } else {
            coef = 1.0f / 12.0f + th2 / 720.0f;
        }
        float3 pxt = cross3(phi, te);
        float3 tau = add3(sub3(te, scl3(0.5f, pxt)), scl3(coef, cross3(phi, pxt)));

        float wgt = (eidx[k] == E - 1) ? KEY_EDGE_WEIGHT : 1.0f;
        res[k][0] = tau.x * wgt;
        res[k][1] = tau.y * wgt;
        res[k][2] = tau.z * wgt;
        res[k][3] = phi.x * wgt;
        res[k][4] = phi.y * wgt;
        res[k][5] = phi.z * wgt;
    }

    // ---- store: 12 contiguous floats = 3x aligned float4 ----
    if (full) {
        float4* o4 = (float4*)(out + (size_t)12 * t);
        o4[0] = make_float4(res[0][0], res[0][1], res[0][2], res[0][3]);
        o4[1] = make_float4(res[0][4], res[0][5], res[1][0], res[1][1]);
        o4[2] = make_float4(res[1][2], res[1][3], res[1][4], res[1][5]);
    } else {
        float* o = out + (size_t)6 * e0;
        *(float2*)(o + 0) = make_float2(res[0][0], res[0][1]);
        *(float2*)(o + 2) = make_float2(res[0][2], res[0][3]);
        *(float2*)(o + 4) = make_float2(res[0][4], res[0][5]);
    }
}

extern "C" void kernel_launch(void* const* d_in, const int* in_sizes, int n_in,
                              void* d_out, int out_size, void* d_ws, size_t ws_size,
                              hipStream_t stream) {
    const float* nodes = (const float*)d_in[0];   // [N,7]
    const float* poses = (const float*)d_in[1];   // [E,4,4]
    const int*   edges = (const int*)d_in[2];     // [E,2] int32
    float* out = (float*)d_out;

    int E = in_sizes[2] / 2;
    int threads = 256;
    int nthreads_total = (E + 1) / 2;             // 2 edges per thread
    int blocks = (nthreads_total + threads - 1) / threads;
    PoseGraph_kernel<<<blocks, threads, 0, stream>>>(nodes, poses, edges, out, E);
}

// Round 6
// 71.461 us; speedup vs baseline: 1.0614x; 1.0614x over previous
//
#include <hip/hip_runtime.h>

#define K_EPS2 1e-8f
#define K_TINY 1e-12f
#define KEY_EDGE_WEIGHT 0.1f

typedef float  vf4 __attribute__((ext_vector_type(4)));
typedef float  vf2 __attribute__((ext_vector_type(2)));
typedef int    vi2 __attribute__((ext_vector_type(2)));

__device__ __forceinline__ float3 f3(float x, float y, float z) { return make_float3(x, y, z); }
__device__ __forceinline__ float3 add3(float3 a, float3 b) { return f3(a.x + b.x, a.y + b.y, a.z + b.z); }
__device__ __forceinline__ float3 sub3(float3 a, float3 b) { return f3(a.x - b.x, a.y - b.y, a.z - b.z); }
__device__ __forceinline__ float3 scl3(float s, float3 a) { return f3(s * a.x, s * a.y, s * a.z); }
__device__ __forceinline__ float dot3(float3 a, float3 b) { return a.x * b.x + a.y * b.y + a.z * b.z; }
__device__ __forceinline__ float3 cross3(float3 a, float3 b) {
    return f3(a.y * b.z - a.z * b.y,
              a.z * b.x - a.x * b.z,
              a.x * b.y - a.y * b.x);
}

__device__ __forceinline__ float3 qrot(float3 qv, float qw, float3 v) {
    float3 t = add3(cross3(qv, v), scl3(qw, v));
    return add3(v, scl3(2.0f, cross3(qv, t)));
}

__device__ __forceinline__ void qmul(float3 v1, float w1, float3 v2, float w2,
                                     float3* v, float* w) {
    *w = w1 * w2 - dot3(v1, v2);
    *v = add3(add3(scl3(w1, v2), scl3(w2, v1)), cross3(v1, v2));
}

// Pre-pass: pack [N,7] nodes into 32B-aligned [N,8] so gathers are 2x float4.
__global__ __launch_bounds__(256) void pack_nodes_kernel(
    const float* __restrict__ nodes, float* __restrict__ packed, int N) {
    int i = blockIdx.x * blockDim.x + threadIdx.x;
    if (i >= N) return;
    const float* p = nodes + (size_t)7 * i;
    vf4 a = { p[0], p[1], p[2], p[3] };
    vf4 b = { p[4], p[5], p[6], 0.0f };
    vf4* o = (vf4*)(packed + (size_t)8 * i);
    o[0] = a;   // cached normally: this table must stay L2-resident
    o[1] = b;
}

template <bool PACKED>
__global__ __launch_bounds__(256) void PoseGraph_kernel(
    const float* __restrict__ nodes,   // PACKED ? [N,8] : [N,7]
    const float* __restrict__ poses,   // [E,4,4] row-major (streamed, nt)
    const int*   __restrict__ edges,   // [E,2]  int32 (streamed, nt)
    float*       __restrict__ out,     // [E,6]  (streamed, nt)
    int E) {
    int e = blockIdx.x * blockDim.x + threadIdx.x;
    if (e >= E) return;

    // ---- edge indices: streamed once, non-temporal ----
    vi2 ij = __builtin_nontemporal_load((const vi2*)(edges + (size_t)2 * e));

    // ---- node gathers (keep cached: table is L2-resident) ----
    float3 t1, q1v, t2, q2v;
    float q1w, q2w;
    if (PACKED) {
        const vf4* pa = (const vf4*)(nodes + (size_t)8 * ij.x);
        const vf4* pb = (const vf4*)(nodes + (size_t)8 * ij.y);
        vf4 a0 = pa[0], a1 = pa[1];
        vf4 b0 = pb[0], b1 = pb[1];
        t1  = f3(a0.x, a0.y, a0.z);
        q1v = f3(a0.w, a1.x, a1.y);
        q1w = a1.z;
        t2  = f3(b0.x, b0.y, b0.z);
        q2v = f3(b0.w, b1.x, b1.y);
        q2w = b1.z;
    } else {
        const float* pa = nodes + (size_t)7 * ij.x;
        const float* pb = nodes + (size_t)7 * ij.y;
        t1  = f3(pa[0], pa[1], pa[2]);
        q1v = f3(pa[3], pa[4], pa[5]);
        q1w = pa[6];
        t2  = f3(pb[0], pb[1], pb[2]);
        q2v = f3(pb[3], pb[4], pb[5]);
        q2w = pb[6];
    }

    // ---- pose rows: streamed once, non-temporal (don't thrash L2) ----
    const vf4* p4 = (const vf4*)(poses + (size_t)e * 16);
    vf4 r0 = __builtin_nontemporal_load(p4 + 0);
    vf4 r1 = __builtin_nontemporal_load(p4 + 1);
    vf4 r2 = __builtin_nontemporal_load(p4 + 2);

    // ---- relative node transform: q1i = conj(q1) ----
    float3 q1iv = f3(-q1v.x, -q1v.y, -q1v.z);
    float3 t12 = qrot(q1iv, q1w, sub3(t2, t1));
    float3 q12v; float q12w;
    qmul(q1iv, q1w, q2v, q2w, &q12v, &q12w);

    // ---- pose matrix -> (tp, qp), branchless copysign mat2SE3 ----
    float m00 = r0.x, m01 = r0.y, m02 = r0.z;
    float m10 = r1.x, m11 = r1.y, m12 = r1.z;
    float m20 = r2.x, m21 = r2.y, m22 = r2.z;
    float3 tp = f3(r0.w, r1.w, r2.w);

    float qpw = 0.5f * sqrtf(fmaxf(1.0f + m00 + m11 + m22, K_TINY));
    float qpx = ((m21 - m12 >= 0.0f) ? 0.5f : -0.5f) * sqrtf(fmaxf(1.0f + m00 - m11 - m22, K_TINY));
    float qpy = ((m02 - m20 >= 0.0f) ? 0.5f : -0.5f) * sqrtf(fmaxf(1.0f - m00 + m11 - m22, K_TINY));
    float qpz = ((m10 - m01 >= 0.0f) ? 0.5f : -0.5f) * sqrtf(fmaxf(1.0f - m00 - m11 + m22, K_TINY));
    float3 qpv = f3(qpx, qpy, qpz);

    // ---- compose error transform ----
    float3 te = add3(tp, qrot(qpv, qpw, t12));
    float3 qev; float qew;
    qmul(qpv, qpw, q12v, q12w, &qev, &qew);

    // ---- SO3 log ----
    float s = (qew < 0.0f) ? -1.0f : 1.0f;
    float3 v = scl3(s, qev);
    float w = s * qew;
    float nn2 = dot3(v, v);
    float scale;
    if (nn2 > K_EPS2) {
        float n = sqrtf(nn2);
        scale = 2.0f * atan2f(n, w) / n;
    } else {
        scale = 2.0f / w - 2.0f * nn2 / (3.0f * w * w * w);
    }
    float3 phi = scl3(scale, v);

    // ---- SE3 log tail: V^{-1} * t ----
    float th2 = dot3(phi, phi);
    float coef;
    if (th2 > K_EPS2) {
        float th = sqrtf(th2);
        float half = 0.5f * th;
        float sh = sinf(half);
        float ch = cosf(half);
        coef = (1.0f - half * ch / sh) / th2;
    } else {
        coef = 1.0f / 12.0f + th2 / 720.0f;
    }
    float3 pxt = cross3(phi, te);
    float3 tau = add3(sub3(te, scl3(0.5f, pxt)), scl3(coef, cross3(phi, pxt)));

    // ---- weight (last edge is the key edge) ----
    float wgt = (e == E - 1) ? KEY_EDGE_WEIGHT : 1.0f;

    // ---- store 24B as 3x float2, non-temporal (write-once stream) ----
    float* o = out + (size_t)6 * e;
    vf2 o0 = { tau.x * wgt, tau.y * wgt };
    vf2 o1 = { tau.z * wgt, phi.x * wgt };
    vf2 o2 = { phi.y * wgt, phi.z * wgt };
    __builtin_nontemporal_store(o0, (vf2*)(o + 0));
    __builtin_nontemporal_store(o1, (vf2*)(o + 2));
    __builtin_nontemporal_store(o2, (vf2*)(o + 4));
}

extern "C" void kernel_launch(void* const* d_in, const int* in_sizes, int n_in,
                              void* d_out, int out_size, void* d_ws, size_t ws_size,
                              hipStream_t stream) {
    const float* nodes = (const float*)d_in[0];   // [N,7]
    const float* poses = (const float*)d_in[1];   // [E,4,4]
    const int*   edges = (const int*)d_in[2];     // [E,2] int32
    float* out = (float*)d_out;

    int N = in_sizes[0] / 7;
    int E = in_sizes[2] / 2;
    int threads = 256;
    int eblocks = (E + threads - 1) / threads;

    size_t packed_bytes = (size_t)N * 8 * sizeof(float);
    if (ws_size >= packed_bytes) {
        float* packed = (float*)d_ws;
        int nblocks = (N + threads - 1) / threads;
        pack_nodes_kernel<<<nblocks, threads, 0, stream>>>(nodes, packed, N);
        PoseGraph_kernel<true><<<eblocks, threads, 0, stream>>>(packed, poses, edges, out, E);
    } else {
        PoseGraph_kernel<false><<<eblocks, threads, 0, stream>>>(nodes, poses, edges, out, E);
    }
}

// Round 7
// 62.472 us; speedup vs baseline: 1.2141x; 1.1439x over previous
//
#include <hip/hip_runtime.h>

#define K_EPS2 1e-8f
#define K_TINY 1e-12f
#define KEY_EDGE_WEIGHT 0.1f

// 4-byte-aligned float4: lets us do 16B vector loads at 28B strides
// (gfx950 global_load_dwordx4 supports dword alignment).
typedef float uf4 __attribute__((ext_vector_type(4), aligned(4)));

__device__ __forceinline__ float3 f3(float x, float y, float z) { return make_float3(x, y, z); }
__device__ __forceinline__ float3 add3(float3 a, float3 b) { return f3(a.x + b.x, a.y + b.y, a.z + b.z); }
__device__ __forceinline__ float3 sub3(float3 a, float3 b) { return f3(a.x - b.x, a.y - b.y, a.z - b.z); }
__device__ __forceinline__ float3 scl3(float s, float3 a) { return f3(s * a.x, s * a.y, s * a.z); }
__device__ __forceinline__ float dot3(float3 a, float3 b) { return a.x * b.x + a.y * b.y + a.z * b.z; }
__device__ __forceinline__ float3 cross3(float3 a, float3 b) {
    return f3(a.y * b.z - a.z * b.y,
              a.z * b.x - a.x * b.z,
              a.x * b.y - a.y * b.x);
}

__device__ __forceinline__ float3 qrot(float3 qv, float qw, float3 v) {
    float3 t = add3(cross3(qv, v), scl3(qw, v));
    return add3(v, scl3(2.0f, cross3(qv, t)));
}

__device__ __forceinline__ void qmul(float3 v1, float w1, float3 v2, float w2,
                                     float3* v, float* w) {
    *w = w1 * w2 - dot3(v1, v2);
    *v = add3(add3(scl3(w1, v2), scl3(w2, v1)), cross3(v1, v2));
}

__global__ __launch_bounds__(256) void PoseGraph_kernel(
    const float* __restrict__ nodes,   // [N,7]  t(3), q(4) xyzw
    const float* __restrict__ poses,   // [E,4,4] row-major
    const int*   __restrict__ edges,   // [E,2]  int32
    float*       __restrict__ out,     // [E,6]  tau(3), phi(3)
    int E) {
    int e = blockIdx.x * blockDim.x + threadIdx.x;
    if (e >= E) return;

    // ---- edge indices (8B aligned int2 load) ----
    int2 ij = *(const int2*)(edges + (size_t)2 * e);

    // ---- node gathers: 2 overlapping 16B vector loads per node ----
    // floats [7i..7i+3] = {tx,ty,tz,qx}, [7i+3..7i+6] = {qx,qy,qz,qw}
    const float* pa = nodes + (size_t)7 * ij.x;
    const float* pb = nodes + (size_t)7 * ij.y;
    uf4 a0 = *(const uf4*)(pa);
    uf4 a1 = *(const uf4*)(pa + 3);
    uf4 b0 = *(const uf4*)(pb);
    uf4 b1 = *(const uf4*)(pb + 3);

    float3 t1  = f3(a0.x, a0.y, a0.z);
    float3 q1v = f3(a1.x, a1.y, a1.z);
    float  q1w = a1.w;
    float3 t2  = f3(b0.x, b0.y, b0.z);
    float3 q2v = f3(b1.x, b1.y, b1.z);
    float  q2w = b1.w;

    // ---- pose rows (16B aligned, coalesced, normal caching) ----
    const float4* p4 = (const float4*)(poses + (size_t)e * 16);
    float4 r0 = p4[0];
    float4 r1 = p4[1];
    float4 r2 = p4[2];

    // ---- relative node transform: q1i = conj(q1) ----
    float3 q1iv = f3(-q1v.x, -q1v.y, -q1v.z);
    float3 t12 = qrot(q1iv, q1w, sub3(t2, t1));
    float3 q12v; float q12w;
    qmul(q1iv, q1w, q2v, q2w, &q12v, &q12w);

    // ---- pose matrix -> (tp, qp), branchless copysign mat2SE3 ----
    float m00 = r0.x, m01 = r0.y, m02 = r0.z;
    float m10 = r1.x, m11 = r1.y, m12 = r1.z;
    float m20 = r2.x, m21 = r2.y, m22 = r2.z;
    float3 tp = f3(r0.w, r1.w, r2.w);

    float qpw = 0.5f * sqrtf(fmaxf(1.0f + m00 + m11 + m22, K_TINY));
    float qpx = ((m21 - m12 >= 0.0f) ? 0.5f : -0.5f) * sqrtf(fmaxf(1.0f + m00 - m11 - m22, K_TINY));
    float qpy = ((m02 - m20 >= 0.0f) ? 0.5f : -0.5f) * sqrtf(fmaxf(1.0f - m00 + m11 - m22, K_TINY));
    float qpz = ((m10 - m01 >= 0.0f) ? 0.5f : -0.5f) * sqrtf(fmaxf(1.0f - m00 - m11 + m22, K_TINY));
    float3 qpv = f3(qpx, qpy, qpz);

    // ---- compose error transform ----
    float3 te = add3(tp, qrot(qpv, qpw, t12));
    float3 qev; float qew;
    qmul(qpv, qpw, q12v, q12w, &qev, &qew);

    // ---- SO3 log ----
    float s = (qew < 0.0f) ? -1.0f : 1.0f;
    float3 v = scl3(s, qev);
    float w = s * qew;
    float nn2 = dot3(v, v);
    float scale;
    if (nn2 > K_EPS2) {
        float n = sqrtf(nn2);
        scale = 2.0f * atan2f(n, w) / n;
    } else {
        scale = 2.0f / w - 2.0f * nn2 / (3.0f * w * w * w);
    }
    float3 phi = scl3(scale, v);

    // ---- SE3 log tail: V^{-1} * t ----
    float th2 = dot3(phi, phi);
    float coef;
    if (th2 > K_EPS2) {
        float th = sqrtf(th2);
        float half = 0.5f * th;
        float sh = sinf(half);
        float ch = cosf(half);
        coef = (1.0f - half * ch / sh) / th2;
    } else {
        coef = 1.0f / 12.0f + th2 / 720.0f;
    }
    float3 pxt = cross3(phi, te);
    float3 tau = add3(sub3(te, scl3(0.5f, pxt)), scl3(coef, cross3(phi, pxt)));

    // ---- weight (last edge is the key edge) ----
    float wgt = (e == E - 1) ? KEY_EDGE_WEIGHT : 1.0f;

    // ---- store 24B as 3x float2 (8B aligned) ----
    float* o = out + (size_t)6 * e;
    *(float2*)(o + 0) = make_float2(tau.x * wgt, tau.y * wgt);
    *(float2*)(o + 2) = make_float2(tau.z * wgt, phi.x * wgt);
    *(float2*)(o + 4) = make_float2(phi.y * wgt, phi.z * wgt);
}

extern "C" void kernel_launch(void* const* d_in, const int* in_sizes, int n_in,
                              void* d_out, int out_size, void* d_ws, size_t ws_size,
                              hipStream_t stream) {
    const float* nodes = (const float*)d_in[0];   // [N,7]
    const float* poses = (const float*)d_in[1];   // [E,4,4]
    const int*   edges = (const int*)d_in[2];     // [E,2] int32
    float* out = (float*)d_out;

    int E = in_sizes[2] / 2;
    int threads = 256;
    int blocks = (E + threads - 1) / threads;
    PoseGraph_kernel<<<blocks, threads, 0, stream>>>(nodes, poses, edges, out, E);
}

// Round 8
// 52.286 us; speedup vs baseline: 1.4507x; 1.1948x over previous
//
#include <hip/hip_runtime.h>

#define K_EPS2 1e-8f
#define K_TINY 1e-12f
#define KEY_EDGE_WEIGHT 0.1f

__device__ __forceinline__ float3 f3(float x, float y, float z) { return make_float3(x, y, z); }
__device__ __forceinline__ float3 add3(float3 a, float3 b) { return f3(a.x + b.x, a.y + b.y, a.z + b.z); }
__device__ __forceinline__ float3 sub3(float3 a, float3 b) { return f3(a.x - b.x, a.y - b.y, a.z - b.z); }
__device__ __forceinline__ float3 scl3(float s, float3 a) { return f3(s * a.x, s * a.y, s * a.z); }
__device__ __forceinline__ float dot3(float3 a, float3 b) { return a.x * b.x + a.y * b.y + a.z * b.z; }
__device__ __forceinline__ float3 cross3(float3 a, float3 b) {
    return f3(a.y * b.z - a.z * b.y,
              a.z * b.x - a.x * b.z,
              a.x * b.y - a.y * b.x);
}

__device__ __forceinline__ float3 qrot(float3 qv, float qw, float3 v) {
    float3 t = add3(cross3(qv, v), scl3(qw, v));
    return add3(v, scl3(2.0f, cross3(qv, t)));
}

__device__ __forceinline__ void qmul(float3 v1, float w1, float3 v2, float w2,
                                     float3* v, float* w) {
    *w = w1 * w2 - dot3(v1, v2);
    *v = add3(add3(scl3(w1, v2), scl3(w2, v1)), cross3(v1, v2));
}

// Per-edge operand set (node pair), gathered with scalar dword loads
// (R7 showed scalar gathers beat unaligned dwordx4 at 28B stride).
struct NP {
    float3 t1, q1v, t2, q2v;
    float  q1w, q2w;
};

__device__ __forceinline__ NP load_nodes(const float* __restrict__ nodes, int2 ij) {
    const float* pa = nodes + (size_t)7 * ij.x;
    const float* pb = nodes + (size_t)7 * ij.y;
    NP n;
    n.t1  = f3(pa[0], pa[1], pa[2]);
    n.q1v = f3(pa[3], pa[4], pa[5]);
    n.q1w = pa[6];
    n.t2  = f3(pb[0], pb[1], pb[2]);
    n.q2v = f3(pb[3], pb[4], pb[5]);
    n.q2w = pb[6];
    return n;
}

__device__ __forceinline__ void compute_store(
    float* __restrict__ out, int e, int E,
    const NP& n, float4 r0, float4 r1, float4 r2) {
    // relative node transform, q1i = conj(q1)
    float3 q1iv = f3(-n.q1v.x, -n.q1v.y, -n.q1v.z);
    float3 t12 = qrot(q1iv, n.q1w, sub3(n.t2, n.t1));
    float3 q12v; float q12w;
    qmul(q1iv, n.q1w, n.q2v, n.q2w, &q12v, &q12w);

    // pose matrix -> (tp, qp), branchless copysign mat2SE3
    float m00 = r0.x, m01 = r0.y, m02 = r0.z;
    float m10 = r1.x, m11 = r1.y, m12 = r1.z;
    float m20 = r2.x, m21 = r2.y, m22 = r2.z;
    float3 tp = f3(r0.w, r1.w, r2.w);

    float qpw = 0.5f * sqrtf(fmaxf(1.0f + m00 + m11 + m22, K_TINY));
    float qpx = ((m21 - m12 >= 0.0f) ? 0.5f : -0.5f) * sqrtf(fmaxf(1.0f + m00 - m11 - m22, K_TINY));
    float qpy = ((m02 - m20 >= 0.0f) ? 0.5f : -0.5f) * sqrtf(fmaxf(1.0f - m00 + m11 - m22, K_TINY));
    float qpz = ((m10 - m01 >= 0.0f) ? 0.5f : -0.5f) * sqrtf(fmaxf(1.0f - m00 - m11 + m22, K_TINY));
    float3 qpv = f3(qpx, qpy, qpz);

    // compose error transform
    float3 te = add3(tp, qrot(qpv, qpw, t12));
    float3 qev; float qew;
    qmul(qpv, qpw, q12v, q12w, &qev, &qew);

    // SO3 log
    float s = (qew < 0.0f) ? -1.0f : 1.0f;
    float3 v = scl3(s, qev);
    float w = s * qew;
    float nn2 = dot3(v, v);
    float scale;
    if (nn2 > K_EPS2) {
        float nrm = sqrtf(nn2);
        scale = 2.0f * atan2f(nrm, w) / nrm;
    } else {
        scale = 2.0f / w - 2.0f * nn2 / (3.0f * w * w * w);
    }
    float3 phi = scl3(scale, v);

    // SE3 log tail: V^{-1} * t
    float th2 = dot3(phi, phi);
    float coef;
    if (th2 > K_EPS2) {
        float th = sqrtf(th2);
        float half = 0.5f * th;
        float sh = sinf(half);
        float ch = cosf(half);
        coef = (1.0f - half * ch / sh) / th2;
    } else {
        coef = 1.0f / 12.0f + th2 / 720.0f;
    }
    float3 pxt = cross3(phi, te);
    float3 tau = add3(sub3(te, scl3(0.5f, pxt)), scl3(coef, cross3(phi, pxt)));

    float wgt = (e == E - 1) ? KEY_EDGE_WEIGHT : 1.0f;

    float* o = out + (size_t)6 * e;
    *(float2*)(o + 0) = make_float2(tau.x * wgt, tau.y * wgt);
    *(float2*)(o + 2) = make_float2(tau.z * wgt, phi.x * wgt);
    *(float2*)(o + 4) = make_float2(phi.y * wgt, phi.z * wgt);
}

// Persistent grid-stride waves with software pipeline:
//   depth-2 prefetch of edge indices, depth-1 prefetch of node/pose operands.
// While computing edge e, the gathers+pose for e+S and indices for e+2S are
// in flight — each load gets a full compute section (~500+ cy) of slack.
__global__ __launch_bounds__(256) void PoseGraph_kernel(
    const float* __restrict__ nodes,   // [N,7]  t(3), q(4) xyzw
    const float* __restrict__ poses,   // [E,4,4] row-major
    const int*   __restrict__ edges,   // [E,2]  int32
    float*       __restrict__ out,     // [E,6]  tau(3), phi(3)
    int E) {
    const int S = gridDim.x * blockDim.x;
    int e = blockIdx.x * blockDim.x + threadIdx.x;
    if (e >= E) return;

    // ---- prologue: operands for edge e, indices for e+S ----
    int2 ij = *(const int2*)(edges + (size_t)2 * e);
    const float4* p4 = (const float4*)(poses + (size_t)e * 16);
    float4 r0 = p4[0];
    float4 r1 = p4[1];
    float4 r2 = p4[2];
    NP cur = load_nodes(nodes, ij);

    int e1 = e + S;
    int2 ij1 = ij;
    if (e1 < E) ij1 = *(const int2*)(edges + (size_t)2 * e1);

    while (e1 < E) {
        // ---- prefetch operands for e1 (indices already resolved) ----
        NP nxt = load_nodes(nodes, ij1);
        const float4* q4 = (const float4*)(poses + (size_t)e1 * 16);
        float4 s0 = q4[0];
        float4 s1 = q4[1];
        float4 s2 = q4[2];

        // ---- prefetch indices for e2 (depth-2) ----
        int e2 = e1 + S;
        int2 ij2 = ij1;
        if (e2 < E) ij2 = *(const int2*)(edges + (size_t)2 * e2);

        // ---- compute edge e while prefetches are in flight ----
        compute_store(out, e, E, cur, r0, r1, r2);

        // ---- rotate pipeline ----
        cur = nxt;
        r0 = s0; r1 = s1; r2 = s2;
        e = e1; e1 = e2; ij1 = ij2;
    }

    // ---- epilogue: last edge ----
    compute_store(out, e, E, cur, r0, r1, r2);
}

extern "C" void kernel_launch(void* const* d_in, const int* in_sizes, int n_in,
                              void* d_out, int out_size, void* d_ws, size_t ws_size,
                              hipStream_t stream) {
    const float* nodes = (const float*)d_in[0];   // [N,7]
    const float* poses = (const float*)d_in[1];   // [E,4,4]
    const int*   edges = (const int*)d_in[2];     // [E,2] int32
    float* out = (float*)d_out;

    int E = in_sizes[2] / 2;
    int threads = 256;
    // Persistent: 8 blocks/CU x 256 CUs = full residency; each thread
    // grid-strides ~4 edges, amortizing its memory-latency prologue.
    int blocks = 2048;
    int max_blocks = (E + threads - 1) / threads;
    if (blocks > max_blocks) blocks = max_blocks;
    PoseGraph_kernel<<<blocks, threads, 0, stream>>>(nodes, poses, edges, out, E);
}